// Round 5
// baseline (392.653 us; speedup 1.0000x reference)
//
#include <hip/hip_runtime.h>
#include <hip/hip_bf16.h>
#include <cstdint>
#include <cstddef>

#define D_MODEL 1024
#define N_HEADS 16
#define D_STATE 64
#define SEQ 4096
#define BATCH 4
#define M_TOK (BATCH * SEQ)          // 16384 tokens
#define N1 4096                      // fused [Wg | p] output width
#define CLEN 64                      // scan chunk length
#define NCH (SEQ / CLEN)             // 64 chunks per sequence
#define NCHAN (BATCH * D_MODEL)      // 4096 scan channels

typedef __attribute__((ext_vector_type(8))) short bf16x8;
typedef __attribute__((ext_vector_type(4))) short bf16x4;
typedef __attribute__((ext_vector_type(4))) float f32x4;

__device__ __forceinline__ float sigmoidf_(float x) {
    return 1.0f / (1.0f + __expf(-x));
}
__device__ __forceinline__ float b2f(short s) {
    union { float f; unsigned u; } v; v.u = ((unsigned)(unsigned short)s) << 16;
    return v.f;
}
__device__ __forceinline__ short f2b(float f) {
    __hip_bfloat16 h = __float2bfloat16(f);
    return *(short*)&h;
}

__device__ __forceinline__ void async_load16(const void* g, void* l) {
    __builtin_amdgcn_global_load_lds(
        (__attribute__((address_space(1))) void*)(g),
        (__attribute__((address_space(3))) void*)(l), 16, 0, 0);
}

// ---------------- fused prep: 3 weight transposes + RMSNorm ----------------
// blocks [0,1024): Wg -> W1T rows 0..1023
// blocks [1024,4096): Wp -> W1T rows 1024..4095, col-permuted to block
//     layout: orig col n = h*192 + t*64 + d  ->  row 1024 + t*1024 + h*64 + d
//     (t=0 delta, t=1 B, t=2 C). Scans then address delta/B/C at
//     1024+hd / 2048+hd / 3072+hd with hd = chan&1023.
// blocks [4096,5120): Wo -> WoT
// blocks [5120,21504): rmsnorm rows (m = bid-5120)
__global__ __launch_bounds__(256) void prep_kernel(
    const float* __restrict__ Wg, const float* __restrict__ Wp,
    const float* __restrict__ Wo,
    const float* __restrict__ x, const float* __restrict__ norm_w,
    __hip_bfloat16* __restrict__ W1T, __hip_bfloat16* __restrict__ WoT,
    __hip_bfloat16* __restrict__ xn)
{
    __shared__ float tile[32][33];
    __shared__ float red[4];
    const int bid = blockIdx.x;
    const int tid = threadIdx.x;

    if (bid < 5120) {
        const float* src; __hip_bfloat16* dst; int N, bx, by, perm;
        if (bid < 1024)      { src = Wg; dst = W1T; N = 1024; bx = bid & 31;          by = bid >> 5;          perm = 0; }
        else if (bid < 4096) { int l = bid - 1024; src = Wp; dst = W1T; N = 3072; bx = l % 96; by = l / 96;   perm = 1; }
        else                 { int l = bid - 4096; src = Wo; dst = WoT; N = 1024; bx = l & 31; by = l >> 5;   perm = 0; }
        int n0 = bx * 32, k0 = by * 32;
        int tx = tid & 31, ty = tid >> 5;
#pragma unroll
        for (int j = 0; j < 32; j += 8)
            tile[ty + j][tx] = src[(size_t)(k0 + ty + j) * N + n0 + tx];
        __syncthreads();
#pragma unroll
        for (int j = 0; j < 32; j += 8) {
            int n = n0 + ty + j;
            int row;
            if (perm) {
                int ht = n >> 6;                  // h*3 + t
                row = 1024 + (ht % 3) * 1024 + (ht / 3) * 64 + (n & 63);
            } else row = n;
            dst[(size_t)row * D_MODEL + k0 + tx] = __float2bfloat16(tile[tx][ty + j]);
        }
    } else {
        int m = bid - 5120;
        const float4* xr = (const float4*)(x + (size_t)m * D_MODEL);
        float4 v = xr[tid];
        float ss = v.x * v.x + v.y * v.y + v.z * v.z + v.w * v.w;
#pragma unroll
        for (int o = 32; o >= 1; o >>= 1) ss += __shfl_xor(ss, o, 64);
        int wave = tid >> 6, lane = tid & 63;
        if (lane == 0) red[wave] = ss;
        __syncthreads();
        float tot = red[0] + red[1] + red[2] + red[3];
        float scale = rsqrtf(tot * (1.0f / D_MODEL) + 1e-6f);
        const float4* wr = (const float4*)norm_w;
        float4 wv = wr[tid];
        __hip_bfloat16 o4[4];
        o4[0] = __float2bfloat16(wv.x * v.x * scale);
        o4[1] = __float2bfloat16(wv.y * v.y * scale);
        o4[2] = __float2bfloat16(wv.z * v.z * scale);
        o4[3] = __float2bfloat16(wv.w * v.w * scale);
        *(uint64_t*)(xn + (size_t)m * D_MODEL + tid * 4) = *(uint64_t*)o4;
    }
}

// ---------------- 256x256 read-ahead pipelined bf16 MFMA GEMM ----------------
// R4 schedule (verified +10%) + R5 change: swizzled ds_read addressing
// hoisted into 4 per-lane base pointers/tile; slot=(kk*4+fq)^frx splits
// as per-kk lane const F0/F1 + compile-time imm (h*8192 + i*2048), so
// reads emit as base+offset:imm — cuts per-read XOR/shift/add VALU.
// MODE 0: out bf16, bias = (col<1024 ? bg[col] : bp[perm(col-1024)])
// MODE 1: out fp32, bias = bias0[col] + bias1[row*1024+col] (residual)
template <int MODE>
__global__ __launch_bounds__(512, 2) void gemm256(
    const __hip_bfloat16* __restrict__ A,
    const __hip_bfloat16* __restrict__ Bt,
    const float* __restrict__ bias0,
    const float* __restrict__ bias1,
    void* __restrict__ outp, int N, int K)
{
    extern __shared__ short lds[];
    const int tid = threadIdx.x;
    const int wave = tid >> 6, lane = tid & 63;
    const int fr = lane & 15, fq = lane >> 4;
    const int frx = fr & 7;
    const int wm = (wave >> 2) * 128;   // 2 M-halves of waves
    const int wn = (wave & 3) * 64;     // 4 N-quarters

    // bijective XCD swizzle (nwg % 8 == 0 for both modes)
    const int gx = gridDim.x;
    const int nwg = gx * gridDim.y;
    const int orig = blockIdx.y * gx + blockIdx.x;
    const int swz = (orig & 7) * (nwg >> 3) + (orig >> 3);
    const int m0 = (swz / gx) * 256;
    const int n0 = (swz % gx) * 256;

    // staging map: thread t -> row rb (8 threads/row), 16B slot p8.
    // global source slot pre-inverse-swizzled; LDS dest stays linear.
    const int rb = tid >> 3, p8 = tid & 7;
    const int lsl = p8 ^ (rb & 7);
    const short* Ag0 = (const short*)A + (size_t)(m0 + rb) * K + lsl * 8;
    const short* Bg0 = (const short*)Bt + (size_t)(n0 + rb) * K + lsl * 8;
    const int stL = rb * 64 + p8 * 8;

    // per-lane ds_read byte-address components
    const int laneA = (wm + fr) * 128;
    const int laneB = (wn + fr) * 128;
    const int F0 = (fq ^ frx) * 16;
    const int F1 = ((4 + fq) ^ frx) * 16;

    const int NT = K >> 6;              // K-tiles of 64

    f32x4 acc[2][4][4];
#pragma unroll
    for (int h = 0; h < 2; ++h)
#pragma unroll
        for (int i = 0; i < 4; ++i)
#pragma unroll
            for (int j = 0; j < 4; ++j)
                acc[h][i][j] = (f32x4){0.f, 0.f, 0.f, 0.f};

    // prologue: stage tile 0 -> buf0, order B0,B1,B2,B3,A0,A2,A1,A3
    {
        short* la = lds;
        short* lb = lds + 16384;
        async_load16(Bg0 + (size_t)(0 * 64) * K, lb + stL + 0 * 4096);
        async_load16(Bg0 + (size_t)(1 * 64) * K, lb + stL + 1 * 4096);
        async_load16(Bg0 + (size_t)(2 * 64) * K, lb + stL + 2 * 4096);
        async_load16(Bg0 + (size_t)(3 * 64) * K, lb + stL + 3 * 4096);
        async_load16(Ag0 + (size_t)(0 * 64) * K, la + stL + 0 * 4096);
        async_load16(Ag0 + (size_t)(2 * 64) * K, la + stL + 2 * 4096);
        async_load16(Ag0 + (size_t)(1 * 64) * K, la + stL + 1 * 4096);
        async_load16(Ag0 + (size_t)(3 * 64) * K, la + stL + 3 * 4096);
    }
    asm volatile("s_waitcnt vmcnt(2)" ::: "memory");  // b0..b3,a0,a2 landed
    __builtin_amdgcn_s_barrier();
    __builtin_amdgcn_sched_barrier(0);

#define RD(base, off) (*(const bf16x8*)((base) + (off)))
#define STAGE_A(c) async_load16(AgN + (size_t)((c) * 64) * K, laN + stL + (c) * 4096)
#define STAGE_B(c) async_load16(BgN + (size_t)((c) * 64) * K, lbN + stL + (c) * 4096)

    bf16x8 afA[4][2], afB[4][2], b0[2][2], b1[2][2];

    // initial reads tile 0 / P0: A-h0 + b0 (from buf0)
    {
        const char* bA0 = (const char*)lds + laneA + F0;
        const char* bA1 = (const char*)lds + laneA + F1;
        const char* bB0 = (const char*)(lds + 16384) + laneB + F0;
        const char* bB1 = (const char*)(lds + 16384) + laneB + F1;
#pragma unroll
        for (int i = 0; i < 4; ++i) { afA[i][0] = RD(bA0, i * 2048); afA[i][1] = RD(bA1, i * 2048); }
#pragma unroll
        for (int j = 0; j < 2; ++j) { b0[j][0] = RD(bB0, j * 2048); b0[j][1] = RD(bB1, j * 2048); }
    }

    for (int t = 0; t < NT; ++t) {
        const short* Ab = lds + ((t & 1) ? 32768 : 0);
        const short* Bb = Ab + 16384;
        short* laN = lds + ((t & 1) ? 0 : 32768);
        short* lbN = laN + 16384;
        const short* AgN = Ag0 + (size_t)(t + 1) * 64;
        const short* BgN = Bg0 + (size_t)(t + 1) * 64;
        const bool pf = (t + 1 < NT);
        const char* bA0 = (const char*)Ab + laneA + F0;
        const char* bA1 = (const char*)Ab + laneA + F1;
        const char* bB0 = (const char*)Bb + laneB + F0;
        const char* bB1 = (const char*)Bb + laneB + F1;

        // ---- P0: MFMA h0 x b0 ; stage B0,B1(t+1) ; read-ahead b1(t) ----
        if (pf) { STAGE_B(0); STAGE_B(1); }
#pragma unroll
        for (int j = 0; j < 2; ++j) { b1[j][0] = RD(bB0, (2 + j) * 2048); b1[j][1] = RD(bB1, (2 + j) * 2048); }
        __builtin_amdgcn_s_setprio(1);
#pragma unroll
        for (int i = 0; i < 4; ++i)
#pragma unroll
            for (int j = 0; j < 2; ++j) {
                acc[0][i][j] = __builtin_amdgcn_mfma_f32_16x16x32_bf16(afA[i][0], b0[j][0], acc[0][i][j], 0, 0, 0);
                acc[0][i][j] = __builtin_amdgcn_mfma_f32_16x16x32_bf16(afA[i][1], b0[j][1], acc[0][i][j], 0, 0, 0);
            }
        __builtin_amdgcn_s_setprio(0);
        __builtin_amdgcn_sched_barrier(0);

        // ---- P1: MFMA h0 x b1 ; stage B2,B3(t+1) ; gate ; read-ahead afB ----
        if (pf) { STAGE_B(2); STAGE_B(3); }
        if (pf) { asm volatile("s_waitcnt vmcnt(4)" ::: "memory"); }  // a1,a3(t) landed
        else    { asm volatile("s_waitcnt vmcnt(0)" ::: "memory"); }
        __builtin_amdgcn_s_barrier();
        __builtin_amdgcn_sched_barrier(0);
#pragma unroll
        for (int i = 0; i < 4; ++i) { afB[i][0] = RD(bA0, 8192 + i * 2048); afB[i][1] = RD(bA1, 8192 + i * 2048); }
        __builtin_amdgcn_s_setprio(1);
#pragma unroll
        for (int i = 0; i < 4; ++i)
#pragma unroll
            for (int j = 0; j < 2; ++j) {
                acc[0][i][2 + j] = __builtin_amdgcn_mfma_f32_16x16x32_bf16(afA[i][0], b1[j][0], acc[0][i][2 + j], 0, 0, 0);
                acc[0][i][2 + j] = __builtin_amdgcn_mfma_f32_16x16x32_bf16(afA[i][1], b1[j][1], acc[0][i][2 + j], 0, 0, 0);
            }
        __builtin_amdgcn_s_setprio(0);
        __builtin_amdgcn_sched_barrier(0);

        // ---- P2: MFMA h1 x b0 ; stage A0,A2(t+1) ----
        if (pf) { STAGE_A(0); STAGE_A(2); }
        __builtin_amdgcn_s_setprio(1);
#pragma unroll
        for (int i = 0; i < 4; ++i)
#pragma unroll
            for (int j = 0; j < 2; ++j) {
                acc[1][i][j] = __builtin_amdgcn_mfma_f32_16x16x32_bf16(afB[i][0], b0[j][0], acc[1][i][j], 0, 0, 0);
                acc[1][i][j] = __builtin_amdgcn_mfma_f32_16x16x32_bf16(afB[i][1], b0[j][1], acc[1][i][j], 0, 0, 0);
            }
        __builtin_amdgcn_s_setprio(0);
        __builtin_amdgcn_sched_barrier(0);

        // ---- P3: MFMA h1 x b1 ; stage A1,A3(t+1) ; gate ; read-ahead next ----
        if (pf) {
            STAGE_A(1); STAGE_A(3);
            asm volatile("s_waitcnt vmcnt(2)" ::: "memory");  // t+1: b0..b3,a0,a2 landed
            __builtin_amdgcn_s_barrier();
            __builtin_amdgcn_sched_barrier(0);
            const char* nA0 = (const char*)laN + laneA + F0;
            const char* nA1 = (const char*)laN + laneA + F1;
            const char* nB0 = (const char*)lbN + laneB + F0;
            const char* nB1 = (const char*)lbN + laneB + F1;
#pragma unroll
            for (int i = 0; i < 4; ++i) { afA[i][0] = RD(nA0, i * 2048); afA[i][1] = RD(nA1, i * 2048); }
#pragma unroll
            for (int j = 0; j < 2; ++j) { b0[j][0] = RD(nB0, j * 2048); b0[j][1] = RD(nB1, j * 2048); }
        }
        __builtin_amdgcn_s_setprio(1);
#pragma unroll
        for (int i = 0; i < 4; ++i)
#pragma unroll
            for (int j = 0; j < 2; ++j) {
                acc[1][i][2 + j] = __builtin_amdgcn_mfma_f32_16x16x32_bf16(afB[i][0], b1[j][0], acc[1][i][2 + j], 0, 0, 0);
                acc[1][i][2 + j] = __builtin_amdgcn_mfma_f32_16x16x32_bf16(afB[i][1], b1[j][1], acc[1][i][2 + j], 0, 0, 0);
            }
        __builtin_amdgcn_s_setprio(0);
        __builtin_amdgcn_sched_barrier(0);
    }
#undef RD
#undef STAGE_A
#undef STAGE_B

    // epilogue: C/D layout row=fq*4+r, col=fr within 16x16 (m89-verified)
    if constexpr (MODE == 0) {
        __hip_bfloat16* O = (__hip_bfloat16*)outp;
        float bv[4];
#pragma unroll
        for (int j = 0; j < 4; ++j) {
            int gcol = n0 + wn + j * 16 + fr;
            if (gcol < D_MODEL) bv[j] = bias0[gcol];
            else {
                int q = gcol - D_MODEL;
                int tt = q >> 10, hd = q & 1023;
                bv[j] = bias1[(hd >> 6) * 192 + tt * 64 + (hd & 63)];
            }
        }
#pragma unroll
        for (int h = 0; h < 2; ++h)
#pragma unroll
            for (int i = 0; i < 4; ++i)
#pragma unroll
                for (int r = 0; r < 4; ++r) {
                    int grow = m0 + wm + h * 64 + i * 16 + fq * 4 + r;
                    __hip_bfloat16* orow = O + (size_t)grow * N + n0 + wn + fr;
#pragma unroll
                    for (int j = 0; j < 4; ++j)
                        orow[j * 16] = __float2bfloat16(acc[h][i][j][r] + bv[j]);
                }
    } else {
        float* O = (float*)outp;
#pragma unroll
        for (int h = 0; h < 2; ++h)
#pragma unroll
            for (int i = 0; i < 4; ++i)
#pragma unroll
                for (int r = 0; r < 4; ++r) {
                    int grow = m0 + wm + h * 64 + i * 16 + fq * 4 + r;
#pragma unroll
                    for (int j = 0; j < 4; ++j) {
                        int gcol = n0 + wn + j * 16 + fr;
                        O[(size_t)grow * N + gcol] =
                            acc[h][i][j][r] + bias0[gcol] + bias1[(size_t)grow * D_MODEL + gcol];
                    }
                }
    }
}

// ---------------- scan pass 1: per-chunk (A = prod sd, B = local scan) ----
// 4 channels/thread, 8B bf16x4 loads. Block layout: delta at 1024+hd,
// B at 2048+hd (prep's permuted W1T).
__global__ __launch_bounds__(256) void scan_part1(
    const __hip_bfloat16* __restrict__ out1,
    float* __restrict__ Abuf, float* __restrict__ Bbuf)
{
    int g = blockIdx.x * 256 + threadIdx.x;  // NCHAN/4 * NCH = 65536
    int cg = g & 1023;                       // channel-group
    int c = g >> 10;                         // chunk
    int chan0 = cg * 4;
    int b = chan0 >> 10, hd0 = chan0 & 1023;
    size_t tok0 = (size_t)b * SEQ + (size_t)c * CLEN;
    const short* pd = (const short*)out1 + tok0 * N1 + D_MODEL + hd0;
    float a[4] = {1.f, 1.f, 1.f, 1.f};
    float hl[4] = {0.f, 0.f, 0.f, 0.f};
#pragma unroll 4
    for (int s = 0; s < CLEN; s++) {
        bf16x4 dv = *(const bf16x4*)pd;
        bf16x4 bv = *(const bf16x4*)(pd + 1024);
#pragma unroll
        for (int k = 0; k < 4; k++) {
            float sd = sigmoidf_(b2f(dv[k]));
            a[k] *= sd;
            hl[k] = sd * hl[k] + b2f(bv[k]);
        }
        pd += N1;
    }
    *(f32x4*)&Abuf[c * NCHAN + chan0] = (f32x4){a[0], a[1], a[2], a[3]};
    *(f32x4*)&Bbuf[c * NCHAN + chan0] = (f32x4){hl[0], hl[1], hl[2], hl[3]};
}

// ---------------- scan pass 2+3 fused: prescan combine + apply ----------
// Each thread: redundantly combine chunk summaries 0..c-1 (L2-resident,
// <=63 float4-pair loads) -> h_in; then token scan + gate/mix. Last-chunk
// threads write new_state. Eliminates scan_comb kernel + Pbuf.
__global__ __launch_bounds__(256) void scan_apply(
    const __hip_bfloat16* __restrict__ out1,
    const __hip_bfloat16* __restrict__ xn,
    const float* __restrict__ Abuf, const float* __restrict__ Bbuf,
    const float* __restrict__ state,
    __hip_bfloat16* __restrict__ mixed, float* __restrict__ new_state)
{
    int g = blockIdx.x * 256 + threadIdx.x;
    int cg = g & 1023;
    int c = g >> 10;
    int chan0 = cg * 4;
    int b = chan0 >> 10, hd0 = chan0 & 1023;
    size_t tok0 = (size_t)b * SEQ + (size_t)c * CLEN;

    f32x4 hp4 = *(const f32x4*)&state[chan0];
    for (int cc = 0; cc < c; ++cc) {
        f32x4 av = *(const f32x4*)&Abuf[cc * NCHAN + chan0];
        f32x4 bv = *(const f32x4*)&Bbuf[cc * NCHAN + chan0];
        hp4 = av * hp4 + bv;
    }
    float hp[4] = {hp4[0], hp4[1], hp4[2], hp4[3]};

    const short* rbase = (const short*)out1 + tok0 * N1;
    const short* xb = (const short*)xn + tok0 * D_MODEL + hd0;
    short* mb = (short*)mixed + tok0 * D_MODEL + hd0;
#pragma unroll 4
    for (int s = 0; s < CLEN; s++) {
        bf16x4 dv = *(const bf16x4*)(rbase + D_MODEL + hd0);
        bf16x4 bv = *(const bf16x4*)(rbase + 2048 + hd0);
        bf16x4 cv = *(const bf16x4*)(rbase + 3072 + hd0);
        bf16x4 gv = *(const bf16x4*)(rbase + hd0);
        bf16x4 xv = *(const bf16x4*)xb;
        bf16x4 ov;
#pragma unroll
        for (int k = 0; k < 4; k++) {
            float sd = sigmoidf_(b2f(dv[k]));
            hp[k] = sd * hp[k] + b2f(bv[k]);
            float gg = sigmoidf_(b2f(gv[k]));
            ov[k] = f2b(gg * (b2f(cv[k]) * hp[k]) + (1.0f - gg) * b2f(xv[k]));
        }
        *(bf16x4*)mb = ov;
        rbase += N1;
        xb += D_MODEL;
        mb += D_MODEL;
    }
    if (c == NCH - 1)
        *(f32x4*)&new_state[chan0] = (f32x4){hp[0], hp[1], hp[2], hp[3]};
}

extern "C" void kernel_launch(void* const* d_in, const int* in_sizes, int n_in,
                              void* d_out, int out_size, void* d_ws, size_t ws_size,
                              hipStream_t stream) {
    const float* x      = (const float*)d_in[0];
    const float* state  = (const float*)d_in[1];
    const float* norm_w = (const float*)d_in[2];
    const float* Wp     = (const float*)d_in[3];
    const float* bp     = (const float*)d_in[4];
    const float* Wg     = (const float*)d_in[5];
    const float* bg     = (const float*)d_in[6];
    const float* Wo     = (const float*)d_in[7];
    const float* bo     = (const float*)d_in[8];
    float* out = (float*)d_out;

    // workspace layout (~203 MB)
    __hip_bfloat16* W1T   = (__hip_bfloat16*)d_ws;                  // 4096 x 1024
    __hip_bfloat16* WoT   = W1T + (size_t)N1 * D_MODEL;             // 1024 x 1024
    __hip_bfloat16* xnb   = WoT + (size_t)D_MODEL * D_MODEL;        // 16384 x 1024
    __hip_bfloat16* out1  = xnb + (size_t)M_TOK * D_MODEL;          // 16384 x 4096
    __hip_bfloat16* mixed = out1 + (size_t)M_TOK * N1;              // 16384 x 1024
    float* Abuf = (float*)(mixed + (size_t)M_TOK * D_MODEL);        // 64 x 4096
    float* Bbuf = Abuf + (size_t)NCHAN * NCH;                       // 64 x 4096

    static bool attr_set = false;
    if (!attr_set) {
        hipFuncSetAttribute(reinterpret_cast<const void*>(&gemm256<0>),
                            hipFuncAttributeMaxDynamicSharedMemorySize, 131072);
        hipFuncSetAttribute(reinterpret_cast<const void*>(&gemm256<1>),
                            hipFuncAttributeMaxDynamicSharedMemorySize, 131072);
        attr_set = true;
    }

    prep_kernel<<<5120 + M_TOK, 256, 0, stream>>>(
        Wg, Wp, Wo, x, norm_w, W1T, WoT, xnb);

    gemm256<0><<<dim3(N1 / 256, M_TOK / 256), 512, 131072, stream>>>(
        xnb, W1T, bg, bp, (void*)out1, N1, D_MODEL);

    scan_part1<<<(NCHAN / 4 * NCH) / 256, 256, 0, stream>>>(out1, Abuf, Bbuf);

    scan_apply<<<(NCHAN / 4 * NCH) / 256, 256, 0, stream>>>(
        out1, xnb, Abuf, Bbuf, state, mixed, out + (size_t)M_TOK * D_MODEL);

    gemm256<1><<<dim3(D_MODEL / 256, M_TOK / 256), 512, 131072, stream>>>(
        mixed, WoT, bo, x, (void*)out, D_MODEL, D_MODEL);
}